// Round 2
// baseline (501.614 us; speedup 1.0000x reference)
//
#include <hip/hip_runtime.h>
#include <stdint.h>

// Problem dims (fixed)
constexpr int T_DIM  = 16384;
constexpr int IN_DIM = 4096;
constexpr int OUT_DIM = 4096;

constexpr int BM = 128;
constexpr int BN = 128;
constexpr int BK = 128;               // bytes (=int8 elems) of K per tile
constexpr int KTILES = IN_DIM / BK;   // 32

using int32x4 = __attribute__((ext_vector_type(4))) int;

#define GLOAD_LDS16(g, l)                                                     \
    __builtin_amdgcn_global_load_lds(                                         \
        (const __attribute__((address_space(1))) void*)(uintptr_t)(g),        \
        (__attribute__((address_space(3))) void*)(uintptr_t)(l), 16, 0, 0)

// ---------------------------------------------------------------------------
// Pre-pass: int32 (values in [-128,127]) -> packed int8, with the 16B-chunk
// XOR swizzle baked into the global layout so the GEMM can use linear
// global_load_lds and conflict-free ds_read_b128.
// stored chunk (within each 128B group) = logical_chunk ^ (row & 7)
// ---------------------------------------------------------------------------
__global__ void pack_swz(const int* __restrict__ src, int8_t* __restrict__ dst,
                         int rows, int cols) {
    int64_t tid = (int64_t)blockIdx.x * blockDim.x + threadIdx.x;
    int64_t nchunks = (int64_t)rows * (cols / 16);
    if (tid >= nchunks) return;
    int row  = (int)(tid / (cols / 16));
    int cidx = (int)(tid % (cols / 16));  // logical 16B chunk index in row
    const int32x4* s4 =
        reinterpret_cast<const int32x4*>(src + (int64_t)row * cols + (cidx << 4));
    uint32_t p[4];
#pragma unroll
    for (int v = 0; v < 4; ++v) {
        int32x4 t = s4[v];
        p[v] = (uint32_t)(t[0] & 0xff) | ((uint32_t)(t[1] & 0xff) << 8) |
               ((uint32_t)(t[2] & 0xff) << 16) | ((uint32_t)(t[3] & 0xff) << 24);
    }
    int cs = (cidx & ~7) | ((cidx & 7) ^ (row & 7));
    *reinterpret_cast<int32x4*>(dst + (int64_t)row * cols + (cs << 4)) =
        *reinterpret_cast<int32x4*>(p);
}

// ---------------------------------------------------------------------------
// Main GEMM: C[t,o] = sum_k x8[t,k] * w8[o,k]  (both K-contiguous, "B^T" form)
// 128x128 tile, BK=128, 4 waves, each wave = 64x64 = 4x4 fragments of
// mfma_i32_16x16x64_i8. m97-style: global_load_lds staging + 2 barriers/K-step.
// PACKED=true: reads pre-packed+pre-swizzled int8 from d_ws via global_load_lds.
// PACKED=false: fallback — reads int32 inputs, packs in regs, swizzled ds_write.
// Output: int8 values stored as int32 (harness reads d_out as np.int32).
// ---------------------------------------------------------------------------
template <bool PACKED>
__global__ __launch_bounds__(256)
void gemm_i8(const int8_t* __restrict__ x8, const int8_t* __restrict__ w8,
             const int* __restrict__ x32, const int* __restrict__ w32,
             const int* __restrict__ bias, const float* __restrict__ alphap,
             const float* __restrict__ betap, int* __restrict__ out) {
    __shared__ int8_t lA[BM * BK];  // 16 KiB
    __shared__ int8_t lB[BN * BK];  // 16 KiB

    const int tid  = threadIdx.x;
    const int wid  = tid >> 6;   // wave 0..3
    const int lane = tid & 63;

    // XCD-chunked bijective block swizzle (nwg=4096, %8==0)
    const int nwg = gridDim.x;
    const int cpx = nwg >> 3;
    const int bid = blockIdx.x;
    const int swz = (bid & 7) * cpx + (bid >> 3);
    const int bm = swz >> 5;            // OUT/BN = 32 column-blocks
    const int bn = swz & 31;
    const int brow = bm * BM;
    const int bcol = bn * BN;

    const int wr = wid >> 1;  // 0..1 : wave row within 2x2 wave grid
    const int wc = wid & 1;   // 0..1

    const float alpha = *alphap;
    const float beta  = *betap;

    int32x4 acc[4][4] = {};

    for (int kt = 0; kt < KTILES; ++kt) {
        const int64_t kbase = (int64_t)kt * BK;
        if constexpr (PACKED) {
#pragma unroll
            for (int q = 0; q < 4; ++q) {
                const int off   = wid * 4096 + q * 1024 + lane * 16;
                const int row   = off >> 7;    // tile row
                const int inrow = off & 127;   // byte within (pre-swizzled) row
                const int8_t* ga = x8 + (int64_t)(brow + row) * IN_DIM + kbase + inrow;
                const int8_t* gb = w8 + (int64_t)(bcol + row) * IN_DIM + kbase + inrow;
                GLOAD_LDS16(ga, lA + off);
                GLOAD_LDS16(gb, lB + off);
            }
        } else {
#pragma unroll
            for (int q = 0; q < 4; ++q) {
                const int off = wid * 4096 + q * 1024 + lane * 16;
                const int row = off >> 7;
                const int k   = off & 127;     // logical k within tile (mult of 16)
                const int* ga = x32 + (int64_t)(brow + row) * IN_DIM + kbase + k;
                const int* gb = w32 + (int64_t)(bcol + row) * IN_DIM + kbase + k;
                uint32_t pa[4], pb[4];
#pragma unroll
                for (int v = 0; v < 4; ++v) {
                    int32x4 ta = reinterpret_cast<const int32x4*>(ga)[v];
                    int32x4 tb = reinterpret_cast<const int32x4*>(gb)[v];
                    pa[v] = (uint32_t)(ta[0] & 0xff) | ((uint32_t)(ta[1] & 0xff) << 8) |
                            ((uint32_t)(ta[2] & 0xff) << 16) | ((uint32_t)(ta[3] & 0xff) << 24);
                    pb[v] = (uint32_t)(tb[0] & 0xff) | ((uint32_t)(tb[1] & 0xff) << 8) |
                            ((uint32_t)(tb[2] & 0xff) << 16) | ((uint32_t)(tb[3] & 0xff) << 24);
                }
                const int sc = ((k >> 4) ^ (row & 7)) << 4;
                *reinterpret_cast<int32x4*>(lA + row * BK + sc) =
                    *reinterpret_cast<int32x4*>(pa);
                *reinterpret_cast<int32x4*>(lB + row * BK + sc) =
                    *reinterpret_cast<int32x4*>(pb);
            }
        }
        __syncthreads();

        // compute: 2 K-steps of 64, 4x4 fragments
#pragma unroll
        for (int ks = 0; ks < 2; ++ks) {
            const int g  = lane >> 4;       // 0..3
            const int r  = lane & 15;
            const int lc = ks * 4 + g;      // logical 16B chunk 0..7
            int32x4 af[4], bf[4];
#pragma unroll
            for (int m = 0; m < 4; ++m) {
                const int row = wr * 64 + m * 16 + r;
                const int sc  = lc ^ (row & 7);
                af[m] = *reinterpret_cast<const int32x4*>(lA + row * BK + (sc << 4));
            }
#pragma unroll
            for (int n = 0; n < 4; ++n) {
                const int row = wc * 64 + n * 16 + r;
                const int sc  = lc ^ (row & 7);
                bf[n] = *reinterpret_cast<const int32x4*>(lB + row * BK + (sc << 4));
            }
#pragma unroll
            for (int m = 0; m < 4; ++m)
#pragma unroll
                for (int n = 0; n < 4; ++n)
                    acc[m][n] = __builtin_amdgcn_mfma_i32_16x16x64_i8(
                        af[m], bf[n], acc[m][n], 0, 0, 0);
        }
        __syncthreads();
    }

    // Epilogue: y = acc*alpha + bias*beta, round-half-even, clip,
    // store as INT32 (harness convention for integer outputs).
    // C/D layout: col = lane&15, row = (lane>>4)*4 + reg (dtype-independent).
    const int r4 = (lane >> 4) * 4;
    const int cl = lane & 15;
#pragma unroll
    for (int n = 0; n < 4; ++n) {
        const int col = bcol + wc * 64 + n * 16 + cl;
        const float bterm = (float)bias[col] * beta;
#pragma unroll
        for (int m = 0; m < 4; ++m) {
            const int row0 = brow + wr * 64 + m * 16 + r4;
#pragma unroll
            for (int j = 0; j < 4; ++j) {
                float y = (float)acc[m][n][j] * alpha + bterm;
                y = rintf(y);
                y = fminf(fmaxf(y, -128.0f), 127.0f);
                out[(int64_t)(row0 + j) * OUT_DIM + col] = (int)y;
            }
        }
    }
}

// ---------------------------------------------------------------------------
extern "C" void kernel_launch(void* const* d_in, const int* in_sizes, int n_in,
                              void* d_out, int out_size, void* d_ws, size_t ws_size,
                              hipStream_t stream) {
    const int*   x     = (const int*)d_in[0];
    const int*   w     = (const int*)d_in[1];
    const int*   bias  = (const int*)d_in[2];
    const float* alpha = (const float*)d_in[3];
    const float* beta  = (const float*)d_in[4];
    int*         out   = (int*)d_out;

    const size_t need = (size_t)T_DIM * IN_DIM + (size_t)OUT_DIM * IN_DIM;
    const int grid = (T_DIM / BM) * (OUT_DIM / BN);  // 128*32 = 4096

    if (ws_size >= need) {
        int8_t* x8 = (int8_t*)d_ws;
        int8_t* w8 = x8 + (size_t)T_DIM * IN_DIM;
        {
            int64_t nch = (int64_t)T_DIM * (IN_DIM / 16);
            pack_swz<<<(int)((nch + 255) / 256), 256, 0, stream>>>(x, x8, T_DIM, IN_DIM);
        }
        {
            int64_t nch = (int64_t)OUT_DIM * (IN_DIM / 16);
            pack_swz<<<(int)((nch + 255) / 256), 256, 0, stream>>>(w, w8, OUT_DIM, IN_DIM);
        }
        gemm_i8<true><<<grid, 256, 0, stream>>>(x8, w8, nullptr, nullptr,
                                                bias, alpha, beta, out);
    } else {
        gemm_i8<false><<<grid, 256, 0, stream>>>(nullptr, nullptr, x, w,
                                                 bias, alpha, beta, out);
    }
}

// Round 3
// 406.542 us; speedup vs baseline: 1.2339x; 1.2339x over previous
//
#include <hip/hip_runtime.h>
#include <stdint.h>

// Problem dims (fixed)
constexpr int T_DIM   = 16384;
constexpr int IN_DIM  = 4096;
constexpr int OUT_DIM = 4096;

using int32x4 = __attribute__((ext_vector_type(4))) int;

#define GLOAD_LDS16(g, l)                                                     \
    __builtin_amdgcn_global_load_lds(                                         \
        (const __attribute__((address_space(1))) void*)(uintptr_t)(g),        \
        (__attribute__((address_space(3))) void*)(uintptr_t)(l), 16, 0, 0)

// ===========================================================================
// Pre-pass: int32 (int8-valued) -> packed int8, pre-swizzled for the 256^2
// pipeline: within each 64-B group of 4 chunks, stored = chunk ^ ((row>>1)&3).
// (Global pre-swizzle + linear LDS + XOR-on-read: guide rule #21.)
// ===========================================================================
__global__ void pack_swz(const int* __restrict__ src, int8_t* __restrict__ dst,
                         int rows, int cols) {
    int64_t tid = (int64_t)blockIdx.x * blockDim.x + threadIdx.x;
    int64_t nchunks = (int64_t)rows * (cols / 16);
    if (tid >= nchunks) return;
    int row  = (int)(tid / (cols / 16));
    int cidx = (int)(tid % (cols / 16));
    const int32x4* s4 =
        reinterpret_cast<const int32x4*>(src + (int64_t)row * cols + (cidx << 4));
    uint32_t p[4];
#pragma unroll
    for (int v = 0; v < 4; ++v) {
        int32x4 t = s4[v];
        p[v] = (uint32_t)(t[0] & 0xff) | ((uint32_t)(t[1] & 0xff) << 8) |
               ((uint32_t)(t[2] & 0xff) << 16) | ((uint32_t)(t[3] & 0xff) << 24);
    }
    int cs = (cidx & ~3) | ((cidx & 3) ^ ((row >> 1) & 3));
    *reinterpret_cast<int32x4*>(dst + (int64_t)row * cols + (cs << 4)) =
        *reinterpret_cast<int32x4*>(p);
}

// ===========================================================================
// Main GEMM: 256x256 tile, BK=64 int8, 8 waves (2Mx4N), per-wave 128x64.
// 4-buffer LDS pipeline (128 KiB), counted vmcnt(8): computing tile t while
// t+1,t+2 in flight and t+3 being issued into t-1's (consumed) buffer.
// 2 phases per K-tile: {ds_read frags | stage 2 gloads | barrier | setprio(1)
// 16 MFMA setprio(0) | barrier}; boundary vmcnt(8) BEFORE the barrier that
// releases waves into tile t+1 (per-wave vmcnt + barrier = all waves landed).
// ===========================================================================
constexpr int BM = 256, BN = 256, BK = 64;
constexpr int NT    = IN_DIM / BK;     // 64
constexpr int ATILE = BM * BK;         // 16 KiB
constexpr int BUFSZ = 2 * ATILE;       // 32 KiB (A + B)

__global__ __launch_bounds__(512, 2)
void gemm_i8_8p(const int8_t* __restrict__ x8, const int8_t* __restrict__ w8,
                const int* __restrict__ bias, const float* __restrict__ alphap,
                const float* __restrict__ betap, int* __restrict__ out) {
    __shared__ __align__(16) int8_t lds[4 * BUFSZ];   // 128 KiB

    const int tid  = threadIdx.x;
    const int lane = tid & 63;
    const int wid  = tid >> 6;
    const int wr   = wid >> 2;   // 0..1
    const int wc   = wid & 3;    // 0..3

    // XCD-chunked bijective swizzle (nwg = 1024, %8==0)
    const int nwg = gridDim.x;
    const int cpx = nwg >> 3;
    const int bid = blockIdx.x;
    const int swz = (bid & 7) * cpx + (bid >> 3);
    const int bm  = swz >> 4;    // 64 M-blocks
    const int bn  = swz & 15;    // 16 N-blocks
    const int brow = bm * BM;
    const int bcol = bn * BN;

    const float alpha = *alphap;
    const float beta  = *betap;

    const int g = lane >> 4;     // K-chunk 0..3 (16 int8 each)
    const int r = lane & 15;

    // stage tile kt's A (resp. B) half into buffer `buf` (2 gloads/thread)
    auto stageA = [&](int kt, int8_t* buf) {
#pragma unroll
        for (int l = 0; l < 2; ++l) {
            const int off = l * 8192 + tid * 16;
            const int row = off >> 6;
            GLOAD_LDS16(x8 + (int64_t)(brow + row) * IN_DIM + kt * BK + (off & 63),
                        buf + off);
        }
    };
    auto stageB = [&](int kt, int8_t* buf) {
#pragma unroll
        for (int l = 0; l < 2; ++l) {
            const int off = l * 8192 + tid * 16;
            const int row = off >> 6;
            GLOAD_LDS16(w8 + (int64_t)(bcol + row) * IN_DIM + kt * BK + (off & 63),
                        buf + ATILE + off);
        }
    };
    // fragment reads (XOR-unswizzle on the 16-B chunk)
    auto ldA = [&](const int8_t* Ab, int m) -> int32x4 {
        const int row = wr * 128 + m * 16 + r;
        const int sc  = g ^ ((row >> 1) & 3);
        return *reinterpret_cast<const int32x4*>(Ab + row * BK + (sc << 4));
    };
    auto ldB = [&](const int8_t* Bb, int n) -> int32x4 {
        const int row = wc * 64 + n * 16 + r;
        const int sc  = g ^ ((row >> 1) & 3);
        return *reinterpret_cast<const int32x4*>(Bb + row * BK + (sc << 4));
    };

    int32x4 acc[8][4] = {};

    // Prologue: tiles 0,1,2 in flight; wait oldest 4 (tile 0) landed.
    stageA(0, lds);            stageB(0, lds);
    stageA(1, lds + BUFSZ);    stageB(1, lds + BUFSZ);
    stageA(2, lds + 2*BUFSZ);  stageB(2, lds + 2*BUFSZ);
    asm volatile("s_waitcnt vmcnt(8)" ::: "memory");
    __builtin_amdgcn_s_barrier();
    __builtin_amdgcn_sched_barrier(0);

#pragma unroll 1
    for (int t = 0; t < NT; ++t) {
        const int8_t* Ab = lds + (t & 3) * BUFSZ;
        const int8_t* Bb = Ab + ATILE;
        int8_t* nxt = lds + ((t + 3) & 3) * BUFSZ;
        const bool pf = (t + 3 < NT);

        int32x4 bf[4], af[4];
        // ---- phase 0: B all n + A m0..3; stage next A-half; MFMA m0..3
#pragma unroll
        for (int n = 0; n < 4; ++n) bf[n] = ldB(Bb, n);
#pragma unroll
        for (int m = 0; m < 4; ++m) af[m] = ldA(Ab, m);
        if (pf) stageA(t + 3, nxt);
        __builtin_amdgcn_s_barrier();
        __builtin_amdgcn_sched_barrier(0);
        __builtin_amdgcn_s_setprio(1);
#pragma unroll
        for (int m = 0; m < 4; ++m)
#pragma unroll
            for (int n = 0; n < 4; ++n)
                acc[m][n] = __builtin_amdgcn_mfma_i32_16x16x64_i8(
                    af[m], bf[n], acc[m][n], 0, 0, 0);
        __builtin_amdgcn_s_setprio(0);
        __builtin_amdgcn_sched_barrier(0);
        __builtin_amdgcn_s_barrier();

        // ---- phase 1: A m4..7; stage next B-half; MFMA m4..7
#pragma unroll
        for (int m = 0; m < 4; ++m) af[m] = ldA(Ab, 4 + m);
        if (pf) stageB(t + 3, nxt);
        __builtin_amdgcn_s_barrier();
        __builtin_amdgcn_sched_barrier(0);
        __builtin_amdgcn_s_setprio(1);
#pragma unroll
        for (int m = 0; m < 4; ++m)
#pragma unroll
            for (int n = 0; n < 4; ++n)
                acc[4 + m][n] = __builtin_amdgcn_mfma_i32_16x16x64_i8(
                    af[m], bf[n], acc[4 + m][n], 0, 0, 0);
        __builtin_amdgcn_s_setprio(0);
        __builtin_amdgcn_sched_barrier(0);

        // ---- tile boundary: ensure tile t+1 landed for THIS wave, then
        // barrier so it holds for ALL waves. Steady state keeps 8 in flight.
        if (t < NT - 3)       { asm volatile("s_waitcnt vmcnt(8)" ::: "memory"); }
        else if (t == NT - 3) { asm volatile("s_waitcnt vmcnt(4)" ::: "memory"); }
        else if (t == NT - 2) { asm volatile("s_waitcnt vmcnt(0)" ::: "memory"); }
        __builtin_amdgcn_s_barrier();
        __builtin_amdgcn_sched_barrier(0);
    }

    // Epilogue: y = acc*alpha + bias*beta, round, clip, store int32.
    // C/D: col = lane&15, row = (lane>>4)*4 + j.
    const int r4 = (lane >> 4) * 4;
    const int cl = lane & 15;
#pragma unroll
    for (int n = 0; n < 4; ++n) {
        const int col = bcol + wc * 64 + n * 16 + cl;
        const float bterm = (float)bias[col] * beta;
#pragma unroll
        for (int m = 0; m < 8; ++m) {
            const int row0 = brow + wr * 128 + m * 16 + r4;
#pragma unroll
            for (int j = 0; j < 4; ++j) {
                float y = (float)acc[m][n][j] * alpha + bterm;
                y = rintf(y);
                y = fminf(fmaxf(y, -128.0f), 127.0f);
                out[(int64_t)(row0 + j) * OUT_DIM + col] = (int)y;
            }
        }
    }
}

// ===========================================================================
// Fallback (ws too small): round-2 kernel, reads int32 inputs directly,
// packs in regs, swizzled ds_write. 128x128 tile. Known-correct.
// ===========================================================================
__global__ __launch_bounds__(256)
void gemm_i8_fb(const int* __restrict__ x32, const int* __restrict__ w32,
                const int* __restrict__ bias, const float* __restrict__ alphap,
                const float* __restrict__ betap, int* __restrict__ out) {
    constexpr int FBM = 128, FBK = 128;
    __shared__ int8_t lA[FBM * FBK];
    __shared__ int8_t lB[FBM * FBK];

    const int tid  = threadIdx.x;
    const int wid  = tid >> 6;
    const int lane = tid & 63;
    const int nwg = gridDim.x;
    const int cpx = nwg >> 3;
    const int bid = blockIdx.x;
    const int swz = (bid & 7) * cpx + (bid >> 3);
    const int brow = (swz >> 5) * FBM;
    const int bcol = (swz & 31) * FBM;
    const int wr = wid >> 1, wc = wid & 1;
    const float alpha = *alphap;
    const float beta  = *betap;

    int32x4 acc[4][4] = {};
    for (int kt = 0; kt < IN_DIM / FBK; ++kt) {
        const int64_t kbase = (int64_t)kt * FBK;
#pragma unroll
        for (int q = 0; q < 4; ++q) {
            const int off = wid * 4096 + q * 1024 + lane * 16;
            const int row = off >> 7;
            const int k   = off & 127;
            const int* ga = x32 + (int64_t)(brow + row) * IN_DIM + kbase + k;
            const int* gb = w32 + (int64_t)(bcol + row) * IN_DIM + kbase + k;
            uint32_t pa[4], pb[4];
#pragma unroll
            for (int v = 0; v < 4; ++v) {
                int32x4 ta = reinterpret_cast<const int32x4*>(ga)[v];
                int32x4 tb = reinterpret_cast<const int32x4*>(gb)[v];
                pa[v] = (uint32_t)(ta[0] & 0xff) | ((uint32_t)(ta[1] & 0xff) << 8) |
                        ((uint32_t)(ta[2] & 0xff) << 16) | ((uint32_t)(ta[3] & 0xff) << 24);
                pb[v] = (uint32_t)(tb[0] & 0xff) | ((uint32_t)(tb[1] & 0xff) << 8) |
                        ((uint32_t)(tb[2] & 0xff) << 16) | ((uint32_t)(tb[3] & 0xff) << 24);
            }
            const int sc = ((k >> 4) ^ (row & 7)) << 4;
            *reinterpret_cast<int32x4*>(lA + row * FBK + sc) = *reinterpret_cast<int32x4*>(pa);
            *reinterpret_cast<int32x4*>(lB + row * FBK + sc) = *reinterpret_cast<int32x4*>(pb);
        }
        __syncthreads();
#pragma unroll
        for (int ks = 0; ks < 2; ++ks) {
            const int gg = lane >> 4, rr = lane & 15;
            const int lc = ks * 4 + gg;
            int32x4 af[4], bf[4];
#pragma unroll
            for (int m = 0; m < 4; ++m) {
                const int row = wr * 64 + m * 16 + rr;
                af[m] = *reinterpret_cast<const int32x4*>(lA + row * FBK + ((lc ^ (row & 7)) << 4));
            }
#pragma unroll
            for (int n = 0; n < 4; ++n) {
                const int row = wc * 64 + n * 16 + rr;
                bf[n] = *reinterpret_cast<const int32x4*>(lB + row * FBK + ((lc ^ (row & 7)) << 4));
            }
#pragma unroll
            for (int m = 0; m < 4; ++m)
#pragma unroll
                for (int n = 0; n < 4; ++n)
                    acc[m][n] = __builtin_amdgcn_mfma_i32_16x16x64_i8(af[m], bf[n], acc[m][n], 0, 0, 0);
        }
        __syncthreads();
    }
    const int r4 = (lane >> 4) * 4;
    const int cl = lane & 15;
#pragma unroll
    for (int n = 0; n < 4; ++n) {
        const int col = bcol + wc * 64 + n * 16 + cl;
        const float bterm = (float)bias[col] * beta;
#pragma unroll
        for (int m = 0; m < 4; ++m) {
            const int row0 = brow + wr * 64 + m * 16 + r4;
#pragma unroll
            for (int j = 0; j < 4; ++j) {
                float y = (float)acc[m][n][j] * alpha + bterm;
                y = rintf(y);
                y = fminf(fmaxf(y, -128.0f), 127.0f);
                out[(int64_t)(row0 + j) * OUT_DIM + col] = (int)y;
            }
        }
    }
}

// ===========================================================================
extern "C" void kernel_launch(void* const* d_in, const int* in_sizes, int n_in,
                              void* d_out, int out_size, void* d_ws, size_t ws_size,
                              hipStream_t stream) {
    const int*   x     = (const int*)d_in[0];
    const int*   w     = (const int*)d_in[1];
    const int*   bias  = (const int*)d_in[2];
    const float* alpha = (const float*)d_in[3];
    const float* beta  = (const float*)d_in[4];
    int*         out   = (int*)d_out;

    const size_t need = (size_t)T_DIM * IN_DIM + (size_t)OUT_DIM * IN_DIM;

    if (ws_size >= need) {
        int8_t* x8 = (int8_t*)d_ws;
        int8_t* w8 = x8 + (size_t)T_DIM * IN_DIM;
        {
            int64_t nch = (int64_t)T_DIM * (IN_DIM / 16);
            pack_swz<<<(int)((nch + 255) / 256), 256, 0, stream>>>(x, x8, T_DIM, IN_DIM);
        }
        {
            int64_t nch = (int64_t)OUT_DIM * (IN_DIM / 16);
            pack_swz<<<(int)((nch + 255) / 256), 256, 0, stream>>>(w, w8, OUT_DIM, IN_DIM);
        }
        const int grid = (T_DIM / BM) * (OUT_DIM / BN);  // 64*16 = 1024
        gemm_i8_8p<<<grid, 512, 0, stream>>>(x8, w8, bias, alpha, beta, out);
    } else {
        const int grid = (T_DIM / 128) * (OUT_DIM / 128);  // 4096
        gemm_i8_fb<<<grid, 256, 0, stream>>>(x, w, bias, alpha, beta, out);
    }
}

// Round 4
// 395.743 us; speedup vs baseline: 1.2675x; 1.0273x over previous
//
#include <hip/hip_runtime.h>
#include <stdint.h>

// Problem dims (fixed)
constexpr int T_DIM   = 16384;
constexpr int IN_DIM  = 4096;
constexpr int OUT_DIM = 4096;

using int32x4 = __attribute__((ext_vector_type(4))) int;

#define GLOAD_LDS16(g, l)                                                     \
    __builtin_amdgcn_global_load_lds(                                         \
        (const __attribute__((address_space(1))) void*)(uintptr_t)(g),        \
        (__attribute__((address_space(3))) void*)(uintptr_t)(l), 16, 0, 0)

// ===========================================================================
// Pre-pass: int32 (int8-valued) -> packed int8, pre-swizzled: within each
// 64-B group of 4 chunks, stored = chunk ^ ((row>>1)&3).  (rule #21)
// ===========================================================================
__global__ void pack_swz(const int* __restrict__ src, int8_t* __restrict__ dst,
                         int rows, int cols) {
    int64_t tid = (int64_t)blockIdx.x * blockDim.x + threadIdx.x;
    int64_t nchunks = (int64_t)rows * (cols / 16);
    if (tid >= nchunks) return;
    int row  = (int)(tid / (cols / 16));
    int cidx = (int)(tid % (cols / 16));
    const int32x4* s4 =
        reinterpret_cast<const int32x4*>(src + (int64_t)row * cols + (cidx << 4));
    uint32_t p[4];
#pragma unroll
    for (int v = 0; v < 4; ++v) {
        int32x4 t = s4[v];
        p[v] = (uint32_t)(t[0] & 0xff) | ((uint32_t)(t[1] & 0xff) << 8) |
               ((uint32_t)(t[2] & 0xff) << 16) | ((uint32_t)(t[3] & 0xff) << 24);
    }
    int cs = (cidx & ~3) | ((cidx & 3) ^ ((row >> 1) & 3));
    *reinterpret_cast<int32x4*>(dst + (int64_t)row * cols + (cs << 4)) =
        *reinterpret_cast<int32x4*>(p);
}

// ===========================================================================
// Main GEMM: 256x256 tile, BK=64 int8, 8 waves (2Mx4N), per-wave 128x64.
// 4-buffer LDS pipeline (128 KiB), counted vmcnt(8). Per K-tile: 2 phases of
// {ds_read frags | stage 2 gloads | BAR | lgkmcnt(0) | prio1 16xMFMA prio0 |
// BAR}; counted vmcnt at tile boundary only. NO sched_barrier(0) pinning
// (m141 lesson) — only one compiler memory fence per tile at the boundary.
// ===========================================================================
constexpr int BM = 256, BN = 256, BK = 64;
constexpr int NT    = IN_DIM / BK;     // 64
constexpr int ATILE = BM * BK;         // 16 KiB
constexpr int BUFSZ = 2 * ATILE;       // 32 KiB (A + B)

__global__ __launch_bounds__(512, 2)
void gemm_i8_8p(const int8_t* __restrict__ x8, const int8_t* __restrict__ w8,
                const int* __restrict__ bias, const float* __restrict__ alphap,
                const float* __restrict__ betap, int* __restrict__ out) {
    __shared__ __align__(16) int8_t lds[4 * BUFSZ];   // 128 KiB

    const int tid  = threadIdx.x;
    const int lane = tid & 63;
    const int wid  = tid >> 6;
    const int wr   = wid >> 2;   // 0..1
    const int wc   = wid & 3;    // 0..3

    // XCD-chunked bijective swizzle (nwg = 1024, %8==0)
    const int nwg = gridDim.x;
    const int cpx = nwg >> 3;
    const int bid = blockIdx.x;
    const int swz = (bid & 7) * cpx + (bid >> 3);
    const int bm  = swz >> 4;    // 64 M-blocks
    const int bn  = swz & 15;    // 16 N-blocks
    const int brow = bm * BM;
    const int bcol = bn * BN;

    const float alpha = *alphap;
    const float beta  = *betap;

    const int g = lane >> 4;     // K-chunk 0..3 (16 int8 each)
    const int r = lane & 15;

    auto stageA = [&](int kt, int8_t* buf) {
#pragma unroll
        for (int l = 0; l < 2; ++l) {
            const int off = l * 8192 + tid * 16;
            const int row = off >> 6;
            GLOAD_LDS16(x8 + (int64_t)(brow + row) * IN_DIM + kt * BK + (off & 63),
                        buf + off);
        }
    };
    auto stageB = [&](int kt, int8_t* buf) {
#pragma unroll
        for (int l = 0; l < 2; ++l) {
            const int off = l * 8192 + tid * 16;
            const int row = off >> 6;
            GLOAD_LDS16(w8 + (int64_t)(bcol + row) * IN_DIM + kt * BK + (off & 63),
                        buf + ATILE + off);
        }
    };
    auto ldA = [&](const int8_t* Ab, int m) -> int32x4 {
        const int row = wr * 128 + m * 16 + r;
        const int sc  = g ^ ((row >> 1) & 3);
        return *reinterpret_cast<const int32x4*>(Ab + row * BK + (sc << 4));
    };
    auto ldB = [&](const int8_t* Bb, int n) -> int32x4 {
        const int row = wc * 64 + n * 16 + r;
        const int sc  = g ^ ((row >> 1) & 3);
        return *reinterpret_cast<const int32x4*>(Bb + row * BK + (sc << 4));
    };

    int32x4 acc[8][4] = {};

    // One K-tile: 2 phases. VM: 8 = steady, 4/0 = drain, -1 = none.
#define KTILE(T, BIDX, PF, VM)                                                 \
    do {                                                                       \
        const int8_t* Ab = lds + (BIDX) * BUFSZ;                               \
        const int8_t* Bb = Ab + ATILE;                                         \
        int8_t* nxt = lds + (((BIDX) + 3) & 3) * BUFSZ;                        \
        int32x4 bf[4], af[4];                                                  \
        _Pragma("unroll") for (int n = 0; n < 4; ++n) bf[n] = ldB(Bb, n);      \
        _Pragma("unroll") for (int m = 0; m < 4; ++m) af[m] = ldA(Ab, m);      \
        if (PF) stageA((T) + 3, nxt);                                          \
        __builtin_amdgcn_s_barrier();                                          \
        asm volatile("s_waitcnt lgkmcnt(0)");                                  \
        __builtin_amdgcn_s_setprio(1);                                         \
        _Pragma("unroll") for (int m = 0; m < 4; ++m)                          \
            _Pragma("unroll") for (int n = 0; n < 4; ++n)                      \
                acc[m][n] = __builtin_amdgcn_mfma_i32_16x16x64_i8(             \
                    af[m], bf[n], acc[m][n], 0, 0, 0);                         \
        __builtin_amdgcn_s_setprio(0);                                         \
        __builtin_amdgcn_s_barrier();                                          \
        _Pragma("unroll") for (int m = 0; m < 4; ++m) af[m] = ldA(Ab, 4 + m);  \
        if (PF) stageB((T) + 3, nxt);                                          \
        __builtin_amdgcn_s_barrier();                                          \
        asm volatile("s_waitcnt lgkmcnt(0)");                                  \
        __builtin_amdgcn_s_setprio(1);                                         \
        _Pragma("unroll") for (int m = 0; m < 4; ++m)                          \
            _Pragma("unroll") for (int n = 0; n < 4; ++n)                      \
                acc[4 + m][n] = __builtin_amdgcn_mfma_i32_16x16x64_i8(         \
                    af[m], bf[n], acc[4 + m][n], 0, 0, 0);                     \
        __builtin_amdgcn_s_setprio(0);                                         \
        if ((VM) == 8)      asm volatile("s_waitcnt vmcnt(8)" ::: "memory");   \
        else if ((VM) == 4) asm volatile("s_waitcnt vmcnt(4)" ::: "memory");   \
        else if ((VM) == 0) asm volatile("s_waitcnt vmcnt(0)" ::: "memory");   \
        __builtin_amdgcn_s_barrier();                                          \
        asm volatile("" ::: "memory"); /* pin stage/reads below boundary */    \
    } while (0)

    // Prologue: tiles 0,1,2 in flight; wait until tile 0 landed.
    stageA(0, lds);            stageB(0, lds);
    stageA(1, lds + BUFSZ);    stageB(1, lds + BUFSZ);
    stageA(2, lds + 2*BUFSZ);  stageB(2, lds + 2*BUFSZ);
    asm volatile("s_waitcnt vmcnt(8)" ::: "memory");
    __builtin_amdgcn_s_barrier();
    asm volatile("" ::: "memory");

    // Main loop: buffer indices are literals (tt % 4 == 0).
#pragma unroll 1
    for (int tt = 0; tt < NT - 4; tt += 4) {
        KTILE(tt + 0, 0, true, 8);
        KTILE(tt + 1, 1, true, 8);
        KTILE(tt + 2, 2, true, 8);
        KTILE(tt + 3, 3, true, 8);
    }
    // Tail: tiles 60..63 (stage 63 during 60; drain 8->4->0).
    KTILE(NT - 4, 0, true,  8);
    KTILE(NT - 3, 1, false, 4);
    KTILE(NT - 2, 2, false, 0);
    KTILE(NT - 1, 3, false, -1);
#undef KTILE

    // Epilogue: y = acc*alpha + bias*beta, round, clip, store int32.
    // C/D: col = lane&15, row = (lane>>4)*4 + j.
    const int r4 = (lane >> 4) * 4;
    const int cl = lane & 15;
#pragma unroll
    for (int n = 0; n < 4; ++n) {
        const int col = bcol + wc * 64 + n * 16 + cl;
        const float bterm = (float)bias[col] * beta;
#pragma unroll
        for (int m = 0; m < 8; ++m) {
            const int row0 = brow + wr * 128 + m * 16 + r4;
#pragma unroll
            for (int j = 0; j < 4; ++j) {
                float y = (float)acc[m][n][j] * alpha + bterm;
                y = rintf(y);
                y = fminf(fmaxf(y, -128.0f), 127.0f);
                out[(int64_t)(row0 + j) * OUT_DIM + col] = (int)y;
            }
        }
    }
}

// ===========================================================================
// Fallback (ws too small): reads int32 inputs directly, packs in regs,
// swizzled ds_write. 128x128 tile. Known-correct (round 2).
// ===========================================================================
__global__ __launch_bounds__(256)
void gemm_i8_fb(const int* __restrict__ x32, const int* __restrict__ w32,
                const int* __restrict__ bias, const float* __restrict__ alphap,
                const float* __restrict__ betap, int* __restrict__ out) {
    constexpr int FBM = 128, FBK = 128;
    __shared__ int8_t lA[FBM * FBK];
    __shared__ int8_t lB[FBM * FBK];

    const int tid  = threadIdx.x;
    const int wid  = tid >> 6;
    const int lane = tid & 63;
    const int nwg = gridDim.x;
    const int cpx = nwg >> 3;
    const int bid = blockIdx.x;
    const int swz = (bid & 7) * cpx + (bid >> 3);
    const int brow = (swz >> 5) * FBM;
    const int bcol = (swz & 31) * FBM;
    const int wr = wid >> 1, wc = wid & 1;
    const float alpha = *alphap;
    const float beta  = *betap;

    int32x4 acc[4][4] = {};
    for (int kt = 0; kt < IN_DIM / FBK; ++kt) {
        const int64_t kbase = (int64_t)kt * FBK;
#pragma unroll
        for (int q = 0; q < 4; ++q) {
            const int off = wid * 4096 + q * 1024 + lane * 16;
            const int row = off >> 7;
            const int k   = off & 127;
            const int* ga = x32 + (int64_t)(brow + row) * IN_DIM + kbase + k;
            const int* gb = w32 + (int64_t)(bcol + row) * IN_DIM + kbase + k;
            uint32_t pa[4], pb[4];
#pragma unroll
            for (int v = 0; v < 4; ++v) {
                int32x4 ta = reinterpret_cast<const int32x4*>(ga)[v];
                int32x4 tb = reinterpret_cast<const int32x4*>(gb)[v];
                pa[v] = (uint32_t)(ta[0] & 0xff) | ((uint32_t)(ta[1] & 0xff) << 8) |
                        ((uint32_t)(ta[2] & 0xff) << 16) | ((uint32_t)(ta[3] & 0xff) << 24);
                pb[v] = (uint32_t)(tb[0] & 0xff) | ((uint32_t)(tb[1] & 0xff) << 8) |
                        ((uint32_t)(tb[2] & 0xff) << 16) | ((uint32_t)(tb[3] & 0xff) << 24);
            }
            const int sc = ((k >> 4) ^ (row & 7)) << 4;
            *reinterpret_cast<int32x4*>(lA + row * FBK + sc) = *reinterpret_cast<int32x4*>(pa);
            *reinterpret_cast<int32x4*>(lB + row * FBK + sc) = *reinterpret_cast<int32x4*>(pb);
        }
        __syncthreads();
#pragma unroll
        for (int ks = 0; ks < 2; ++ks) {
            const int gg = lane >> 4, rr = lane & 15;
            const int lc = ks * 4 + gg;
            int32x4 af[4], bf[4];
#pragma unroll
            for (int m = 0; m < 4; ++m) {
                const int row = wr * 64 + m * 16 + rr;
                af[m] = *reinterpret_cast<const int32x4*>(lA + row * FBK + ((lc ^ (row & 7)) << 4));
            }
#pragma unroll
            for (int n = 0; n < 4; ++n) {
                const int row = wc * 64 + n * 16 + rr;
                bf[n] = *reinterpret_cast<const int32x4*>(lB + row * FBK + ((lc ^ (row & 7)) << 4));
            }
#pragma unroll
            for (int m = 0; m < 4; ++m)
#pragma unroll
                for (int n = 0; n < 4; ++n)
                    acc[m][n] = __builtin_amdgcn_mfma_i32_16x16x64_i8(af[m], bf[n], acc[m][n], 0, 0, 0);
        }
        __syncthreads();
    }
    const int r4 = (lane >> 4) * 4;
    const int cl = lane & 15;
#pragma unroll
    for (int n = 0; n < 4; ++n) {
        const int col = bcol + wc * 64 + n * 16 + cl;
        const float bterm = (float)bias[col] * beta;
#pragma unroll
        for (int m = 0; m < 4; ++m) {
            const int row0 = brow + wr * 64 + m * 16 + r4;
#pragma unroll
            for (int j = 0; j < 4; ++j) {
                float y = (float)acc[m][n][j] * alpha + bterm;
                y = rintf(y);
                y = fminf(fmaxf(y, -128.0f), 127.0f);
                out[(int64_t)(row0 + j) * OUT_DIM + col] = (int)y;
            }
        }
    }
}

// ===========================================================================
extern "C" void kernel_launch(void* const* d_in, const int* in_sizes, int n_in,
                              void* d_out, int out_size, void* d_ws, size_t ws_size,
                              hipStream_t stream) {
    const int*   x     = (const int*)d_in[0];
    const int*   w     = (const int*)d_in[1];
    const int*   bias  = (const int*)d_in[2];
    const float* alpha = (const float*)d_in[3];
    const float* beta  = (const float*)d_in[4];
    int*         out   = (int*)d_out;

    const size_t need = (size_t)T_DIM * IN_DIM + (size_t)OUT_DIM * IN_DIM;

    if (ws_size >= need) {
        int8_t* x8 = (int8_t*)d_ws;
        int8_t* w8 = x8 + (size_t)T_DIM * IN_DIM;
        {
            int64_t nch = (int64_t)T_DIM * (IN_DIM / 16);
            pack_swz<<<(int)((nch + 255) / 256), 256, 0, stream>>>(x, x8, T_DIM, IN_DIM);
        }
        {
            int64_t nch = (int64_t)OUT_DIM * (IN_DIM / 16);
            pack_swz<<<(int)((nch + 255) / 256), 256, 0, stream>>>(w, w8, OUT_DIM, IN_DIM);
        }
        const int grid = (T_DIM / BM) * (OUT_DIM / BN);  // 1024
        gemm_i8_8p<<<grid, 512, 0, stream>>>(x8, w8, bias, alpha, beta, out);
    } else {
        const int grid = (T_DIM / 128) * (OUT_DIM / 128);  // 4096
        gemm_i8_fb<<<grid, 256, 0, stream>>>(x, w, bias, alpha, beta, out);
    }
}